// Round 6
// baseline (146.318 us; speedup 1.0000x reference)
//
#include <hip/hip_runtime.h>
#include <math.h>

#define DIM 2048          // INPUT_DIM
#define NF 2048           // N_FORMULAS
#define LPF 16            // LITERALS_PER_FORMULA
#define LTOT (NF * LPF)   // 32768
#define BETA 0.4f
#define EPS 1.0f
#define NDCH 64           // d-chunks for the reduction
#define DCH (DIM / NDCH)  // 32 rows per chunk

typedef float f32x4 __attribute__((ext_vector_type(4)));

// ---------------------------------------------------------------------------
// Kernel A: per-formula partial reduction + LLC prefetch of both inputs.
// grid = (NF/1024, NDCH), block = 256. float4 loads, fully coalesced.
// Warms the 256 MB Infinity Cache so expand's reads are LLC-hits.
// ws layout: [NDCH][3][NF] floats, then ws2[NF].
// ---------------------------------------------------------------------------
__global__ void reduce_prefetch(const float* __restrict__ lm,
                                const float* __restrict__ frm,
                                float* __restrict__ ws) {
    const int f4 = blockIdx.x * 256 + threadIdx.x;   // float4 index in row, 0..511
    const int d0 = blockIdx.y * DCH;

    const f32x4* lm4 = (const f32x4*)lm;
    const f32x4* fr4 = (const f32x4*)frm;

    f32x4 sq = {0.f, 0.f, 0.f, 0.f};
    f32x4 l1 = {0.f, 0.f, 0.f, 0.f};
    f32x4 cnt = {0.f, 0.f, 0.f, 0.f};

    #pragma unroll 4
    for (int i = 0; i < DCH; ++i) {
        const size_t off = ((size_t)(d0 + i) << 9) + f4;   // row stride = 512 f4
        f32x4 x = lm4[off];
        f32x4 r = fr4[off];
        #pragma unroll
        for (int j = 0; j < 4; ++j) {
            sq[j]  = fmaf(x[j] * x[j], r[j], sq[j]);
            l1[j]  = fmaf(fabsf(x[j]), r[j], l1[j]);
            cnt[j] += r[j];
        }
    }

    float* w = ws + (size_t)blockIdx.y * 3 * NF;
    ((f32x4*)(w + 0 * NF))[f4] = sq;
    ((f32x4*)(w + 1 * NF))[f4] = l1;
    ((f32x4*)(w + 2 * NF))[f4] = cnt;
}

// ---------------------------------------------------------------------------
// Kernel B: pure expansion. R6 change vs R5: PLAIN stores instead of
// nontemporal. fillBufferAligned proves plain full-line streaming stores on
// this exact buffer reach 6.7 TB/s; R4's plain-store regression was the
// cold-read confound (now absent: reads are LLC-warm from kernel A).
// grid = (NF/64, 64), block = 256.
// ---------------------------------------------------------------------------
__global__ void expand_plain(const float* __restrict__ lm,
                             const float* __restrict__ frm,
                             f32x4* __restrict__ out0,
                             f32x4* __restrict__ out1) {
    const int t = threadIdx.x;
    const int f = blockIdx.x * 64 + (t >> 2);
    const int d0 = blockIdx.y * DCH;
    const size_t obase = (size_t)blockIdx.x * 256 + t;   // float4 column index

    #pragma unroll 4
    for (int i = 0; i < DCH; ++i) {
        const int d = d0 + i;
        const size_t in_off = ((size_t)d << 11) + f;     // d*NF + f
        float x = lm[in_off];
        float r = frm[in_off];
        float bin = (fabsf(x) > EPS) ? 1.0f : 0.0f;

        const size_t o = ((size_t)d << 13) + obase;      // d*(LTOT/4) + col
        f32x4 v0 = { bin, bin, bin, bin };
        f32x4 v1 = { r, r, r, r };
        out0[o] = v0;
        out1[o] = v1;
    }
}

// ---------------------------------------------------------------------------
// Kernel C: per-formula term from chunk partials. grid = NF/256 blocks.
// ---------------------------------------------------------------------------
__global__ void formula_term_kernel(const float* __restrict__ ws,
                                    const float* __restrict__ alpha,
                                    float* __restrict__ ws2) {
    const int f = blockIdx.x * blockDim.x + threadIdx.x;
    float sig = 1.0f / (1.0f + expf(-alpha[0]));
    float w_l2 = (1.0f - sig) * 0.5f;
    float w_l1 = sig;

    float sq = 0.0f, l1 = 0.0f, cnt = 0.0f;
    for (int c = 0; c < NDCH; ++c) {
        const float* w = ws + (size_t)c * 3 * NF;
        sq  += w[0 * NF + f];
        l1  += w[1 * NF + f];
        cnt += w[2 * NF + f];
    }
    float l2t = fabsf(sq / cnt - BETA * EPS * EPS);
    float l1t = fabsf(l1 / cnt - BETA * EPS);
    ws2[f] = l2t * w_l2 + l1t * w_l1;
}

// ---------------------------------------------------------------------------
// Kernel D: mean over formulas. 1 block, deterministic LDS tree.
// ---------------------------------------------------------------------------
__global__ void final_sum_kernel(const float* __restrict__ ws2,
                                 float* __restrict__ out_scalar) {
    __shared__ float red[256];
    const int t = threadIdx.x;
    float total = 0.0f;
    for (int k = 0; k < NF / 256; ++k)
        total += ws2[t + k * 256];
    red[t] = total;
    __syncthreads();
    for (int s = 128; s > 0; s >>= 1) {
        if (t < s) red[t] += red[t + s];
        __syncthreads();
    }
    if (t == 0) out_scalar[0] = red[0] / (float)NF;
}

extern "C" void kernel_launch(void* const* d_in, const int* in_sizes, int n_in,
                              void* d_out, int out_size, void* d_ws, size_t ws_size,
                              hipStream_t stream) {
    const float* lm    = (const float*)d_in[0];  // learnable_mask [D, F]
    const float* alpha = (const float*)d_in[1];  // elastic_net_alpha [1]
    const float* frm   = (const float*)d_in[2];  // formulas_random_mask [D, F]
    // d_in[3] = formula_id_per_literal (implicit: l // 16)

    float* out = (float*)d_out;
    float* ws  = (float*)d_ws;   // needs (NDCH*3*NF + NF)*4 = 1.58 MB

    const size_t big = (size_t)DIM * LTOT;       // 67,108,864 per output
    f32x4* out0 = (f32x4*)out;                   // learnable_binary_mask
    f32x4* out1 = (f32x4*)(out + big);           // literals_random_mask
    float* out_scalar = out + 2 * big;           // elastic_net_reg
    float* ws2 = ws + (size_t)NDCH * 3 * NF;

    // A: reduction partials + LLC prefetch of both inputs (reads phase)
    dim3 gridA(NF / 1024, NDCH);
    reduce_prefetch<<<gridA, 256, 0, stream>>>(lm, frm, ws);

    // B: pure plain-store expansion (writes phase; input loads served by LLC)
    dim3 gridB(NF / 64, NDCH);
    expand_plain<<<gridB, 256, 0, stream>>>(lm, frm, out0, out1);

    // C/D: tiny epilogues
    formula_term_kernel<<<NF / 256, 256, 0, stream>>>(ws, alpha, ws2);
    final_sum_kernel<<<1, 256, 0, stream>>>(ws2, out_scalar);
}

// Round 7
// 123.565 us; speedup vs baseline: 1.1841x; 1.1841x over previous
//
#include <hip/hip_runtime.h>
#include <math.h>

#define DIM 2048          // INPUT_DIM
#define NF 2048           // N_FORMULAS
#define LPF 16            // LITERALS_PER_FORMULA
#define LTOT (NF * LPF)   // 32768
#define BETA 0.4f
#define EPS 1.0f
#define NDCH 64           // d-chunks for the reduction
#define DCH (DIM / NDCH)  // 32 rows per chunk

typedef float f32x4 __attribute__((ext_vector_type(4)));

// ---------------------------------------------------------------------------
// Kernel A: per-formula partial reduction + LLC prefetch of both inputs.
// R7: grid (NF/256, NDCH) = 512 blocks (2/CU, was 128). Thread owns ONE
// formula column; loads are scalar but fully coalesced (256 consecutive
// floats per block per row). ws layout unchanged: [NDCH][3][NF], then ws2.
// ---------------------------------------------------------------------------
__global__ void reduce_prefetch(const float* __restrict__ lm,
                                const float* __restrict__ frm,
                                float* __restrict__ ws) {
    const int f = blockIdx.x * 256 + threadIdx.x;    // formula column
    const int d0 = blockIdx.y * DCH;

    float sq = 0.0f, l1 = 0.0f, cnt = 0.0f;
    #pragma unroll 8
    for (int i = 0; i < DCH; ++i) {
        const size_t off = ((size_t)(d0 + i) << 11) + f;   // row stride 2048
        float x = lm[off];
        float r = frm[off];
        sq  = fmaf(x * x, r, sq);
        l1  = fmaf(fabsf(x), r, l1);
        cnt += r;
    }

    float* w = ws + (size_t)blockIdx.y * 3 * NF;
    w[0 * NF + f] = sq;
    w[1 * NF + f] = l1;
    w[2 * NF + f] = cnt;
}

// ---------------------------------------------------------------------------
// Kernel B: pure expansion, nt stores. R7 change: ONE OUTPUT ROW PER BLOCK.
// Block bx < DIM handles out0 row bx; bx >= DIM handles out1 row bx-DIM.
// Each wave's store sequence is pure, monotone-ascending, contiguous
// (fillBuffer-like); per-iter load is a 64B broadcast segment of one input
// row (d constant per block, LLC-warm from kernel A).
// grid = 2*DIM = 4096 blocks, 256 threads, 32 iters (8192 f4 = one row).
// ---------------------------------------------------------------------------
__global__ void expand_stream(const float* __restrict__ lm,
                              const float* __restrict__ frm,
                              f32x4* __restrict__ out0,
                              f32x4* __restrict__ out1) {
    const int t = threadIdx.x;
    const int bx = blockIdx.x;
    const bool is1 = bx >= DIM;
    const int d = is1 ? bx - DIM : bx;
    const float* src = is1 ? frm : lm;
    f32x4* dst = (is1 ? out1 : out0) + ((size_t)d << 13);  // row base, 8192 f4

    const float* row = src + ((size_t)d << 11);

    #pragma unroll 4
    for (int i = 0; i < 32; ++i) {
        const int c = i * 256 + t;        // f4 column within row, 0..8191
        float v = row[c >> 2];            // 4-lane broadcast
        if (!is1) v = (fabsf(v) > EPS) ? 1.0f : 0.0f;
        f32x4 q = { v, v, v, v };
        __builtin_nontemporal_store(q, &dst[c]);
    }
}

// ---------------------------------------------------------------------------
// Kernel C: per-formula term from chunk partials. grid = NF/256 blocks.
// ---------------------------------------------------------------------------
__global__ void formula_term_kernel(const float* __restrict__ ws,
                                    const float* __restrict__ alpha,
                                    float* __restrict__ ws2) {
    const int f = blockIdx.x * blockDim.x + threadIdx.x;
    float sig = 1.0f / (1.0f + expf(-alpha[0]));
    float w_l2 = (1.0f - sig) * 0.5f;
    float w_l1 = sig;

    float sq = 0.0f, l1 = 0.0f, cnt = 0.0f;
    for (int c = 0; c < NDCH; ++c) {
        const float* w = ws + (size_t)c * 3 * NF;
        sq  += w[0 * NF + f];
        l1  += w[1 * NF + f];
        cnt += w[2 * NF + f];
    }
    float l2t = fabsf(sq / cnt - BETA * EPS * EPS);
    float l1t = fabsf(l1 / cnt - BETA * EPS);
    ws2[f] = l2t * w_l2 + l1t * w_l1;
}

// ---------------------------------------------------------------------------
// Kernel D: mean over formulas. 1 block, deterministic LDS tree.
// ---------------------------------------------------------------------------
__global__ void final_sum_kernel(const float* __restrict__ ws2,
                                 float* __restrict__ out_scalar) {
    __shared__ float red[256];
    const int t = threadIdx.x;
    float total = 0.0f;
    for (int k = 0; k < NF / 256; ++k)
        total += ws2[t + k * 256];
    red[t] = total;
    __syncthreads();
    for (int s = 128; s > 0; s >>= 1) {
        if (t < s) red[t] += red[t + s];
        __syncthreads();
    }
    if (t == 0) out_scalar[0] = red[0] / (float)NF;
}

extern "C" void kernel_launch(void* const* d_in, const int* in_sizes, int n_in,
                              void* d_out, int out_size, void* d_ws, size_t ws_size,
                              hipStream_t stream) {
    const float* lm    = (const float*)d_in[0];  // learnable_mask [D, F]
    const float* alpha = (const float*)d_in[1];  // elastic_net_alpha [1]
    const float* frm   = (const float*)d_in[2];  // formulas_random_mask [D, F]
    // d_in[3] = formula_id_per_literal (implicit: l // 16)

    float* out = (float*)d_out;
    float* ws  = (float*)d_ws;   // needs (NDCH*3*NF + NF)*4 = 1.58 MB

    const size_t big = (size_t)DIM * LTOT;       // 67,108,864 per output
    f32x4* out0 = (f32x4*)out;                   // learnable_binary_mask
    f32x4* out1 = (f32x4*)(out + big);           // literals_random_mask
    float* out_scalar = out + 2 * big;           // elastic_net_reg
    float* ws2 = ws + (size_t)NDCH * 3 * NF;

    // A: reduction partials + LLC prefetch of both inputs (reads phase)
    dim3 gridA(NF / 256, NDCH);
    reduce_prefetch<<<gridA, 256, 0, stream>>>(lm, frm, ws);

    // B: pure nt-write expansion, one output row per block (writes phase)
    expand_stream<<<2 * DIM, 256, 0, stream>>>(lm, frm, out0, out1);

    // C/D: tiny epilogues
    formula_term_kernel<<<NF / 256, 256, 0, stream>>>(ws, alpha, ws2);
    final_sum_kernel<<<1, 256, 0, stream>>>(ws2, out_scalar);
}